// Round 7
// baseline (49.886 us; speedup 1.0000x reference)
//
#include <hip/hip_runtime.h>
#include <hip/hip_bf16.h>
#include <stdint.h>

// Locally-connected layer: X[128,32,32,64] f32, filters[900,576,64] f32
// -> out[128,30,30,64] f32.  900 per-location GEMMs: M=128 x N=64 x K=576.
// One WG per location, 512 threads = 8 waves; wave owns a 16x64 output strip.
// R7: A (X) fragments loaded DIRECTLY from global per-lane (fin is innermost
// -> each lane's 8-consecutive-fin A-fragment is two contiguous 16B loads),
// converted f32->bf16 in registers. No A tile in LDS at all. B keeps the
// reg-staged transposed bf16 LDS path (8KB x 2 buffers = 16KB LDS), 1-deep
// prefetch, one lgkmcnt-only barrier per step, XCD-chunked swizzle.
// R2-R6 post-mortem: scheduling tweaks (2-deep ILP, occupancy, vmcnt-across-
// barrier) all null at ~40.5us -> the per-step serial phase pile-up (A staging
// VALU + 104KB/step LDS traffic + conflicts) was the wall. Ablate it.

typedef __attribute__((ext_vector_type(4))) float  f32x4;
typedef __attribute__((ext_vector_type(8))) short  short8;

// XOR swizzle on 16B chunks within a 128B row (B tile only).
__device__ __forceinline__ uint32_t swz_addr(uint32_t row, uint32_t inrow) {
    uint32_t chunk = inrow >> 4;
    uint32_t rem   = inrow & 15u;
    return row * 128u + (((chunk ^ row ^ (row >> 3)) & 7u) << 4) + rem;
}

__device__ __forceinline__ uint16_t f2bf_u(float x) {
    __hip_bfloat16 h = __float2bfloat16(x);
    uint16_t r;
    __builtin_memcpy(&r, &h, 2);
    return r;
}
__device__ __forceinline__ short f2bf(float x) { return (short)f2bf_u(x); }
__device__ __forceinline__ uint32_t pack2bf(float lo, float hi) {
    return (uint32_t)f2bf_u(lo) | ((uint32_t)f2bf_u(hi) << 16);
}

// Barrier that does NOT drain vmcnt (own LDS ops drained; global loads fly).
#define BARRIER_KEEP_VMEM()                                   \
    do {                                                      \
        asm volatile("s_waitcnt lgkmcnt(0)" ::: "memory");    \
        __builtin_amdgcn_s_barrier();                         \
    } while (0)

__global__ __launch_bounds__(512)
void lc_mfma_kernel(const float* __restrict__ X,
                    const float* __restrict__ Fl,
                    float* __restrict__ Out) {
    __shared__ __align__(16) unsigned char lds[2][8192];
    // each buffer: B tile, 64 rows (fout) x 64 bf16 (k of this step), swizzled

    // Bijective XCD-chunked swizzle: 8 XCDs, nwg=900 -> q=112, r=4.
    const int orig = blockIdx.x;
    const int xcd  = orig & 7;
    const int idx  = orig >> 3;
    const int l    = (xcd < 4 ? xcd * 113 : 452 + (xcd - 4) * 112) + idx;

    const int oi = l / 30;
    const int oj = l % 30;
    const int tid  = threadIdx.x;
    const int lane = tid & 63;
    const int wave = tid >> 6;          // 0..7, owns rows wave*16..+15

    f32x4 acc[4];
#pragma unroll
    for (int n = 0; n < 4; ++n)
        acc[n] = f32x4{0.f, 0.f, 0.f, 0.f};

    // A direct-load addressing: lane's A-frag row + fin sub-offset
    const int arow = wave * 16 + (lane & 15);   // batch row
    const int kgrp = (lane >> 4) * 8;           // fin sub-offset (8 floats)
    const float* Abase = X + (size_t)arow * (32 * 32 * 64) + kgrp;

    // B staging (all 512 threads): f block fq*4..+3, k pair kp*2, kp = 0..31
    const int fq = tid & 15;
    const int kp = tid >> 4;            // 0..31
    const float* Fb = Fl + (size_t)l * (576 * 64);

    // ping-pong A prefetch regs (4 float4 = one step's A fragments, f32)
    float4 avA[4], avB[4];
    float4 bv[2];   // B prefetch (2 k-rows x 4 f)

#define ISSUE_A(S, AV)                                                          \
    do {                                                                        \
        const int di_ = (S) / 3, dj_ = (S) % 3;                                 \
        const float* p_ = Abase + ((oi + di_) * 32 + (oj + dj_)) * 64;          \
        AV[0] = *(const float4*)(p_);        AV[1] = *(const float4*)(p_ + 4);  \
        AV[2] = *(const float4*)(p_ + 32);   AV[3] = *(const float4*)(p_ + 36); \
    } while (0)

#define ISSUE_B(S)                                                              \
    do {                                                                        \
        const float* b_ = Fb + (size_t)(S) * 4096 + (size_t)(kp*2) * 64 + fq*4; \
        bv[0] = *(const float4*)(b_);                                           \
        bv[1] = *(const float4*)(b_ + 64);                                      \
    } while (0)

#define WRITE_B(BUF)                                                            \
    do {                                                                        \
        unsigned char* L_ = lds[BUF];                                           \
        /* B transposed: Blds[f][k] bf16; pack (k=kp*2, kp*2+1) into one b32 */ \
        *(uint32_t*)&L_[swz_addr(fq*4 + 0, kp*4)] = pack2bf(bv[0].x, bv[1].x);  \
        *(uint32_t*)&L_[swz_addr(fq*4 + 1, kp*4)] = pack2bf(bv[0].y, bv[1].y);  \
        *(uint32_t*)&L_[swz_addr(fq*4 + 2, kp*4)] = pack2bf(bv[0].z, bv[1].z);  \
        *(uint32_t*)&L_[swz_addr(fq*4 + 3, kp*4)] = pack2bf(bv[0].w, bv[1].w);  \
    } while (0)

#define COMPUTE(L_, AV)                                                         \
    do {                                                                        \
        _Pragma("unroll")                                                       \
        for (int kk = 0; kk < 2; ++kk) {                                        \
            short8 af;                                                          \
            af[0]=f2bf(AV[kk*2].x);   af[1]=f2bf(AV[kk*2].y);                   \
            af[2]=f2bf(AV[kk*2].z);   af[3]=f2bf(AV[kk*2].w);                   \
            af[4]=f2bf(AV[kk*2+1].x); af[5]=f2bf(AV[kk*2+1].y);                 \
            af[6]=f2bf(AV[kk*2+1].z); af[7]=f2bf(AV[kk*2+1].w);                 \
            const uint32_t inrow = (uint32_t)(kk * 64 + ksel);                  \
            const short8 b0 = *(const short8*)&L_[swz_addr(     rsel, inrow)];  \
            const short8 b1 = *(const short8*)&L_[swz_addr(16 + rsel, inrow)];  \
            const short8 b2 = *(const short8*)&L_[swz_addr(32 + rsel, inrow)];  \
            const short8 b3 = *(const short8*)&L_[swz_addr(48 + rsel, inrow)];  \
            acc[0] = __builtin_amdgcn_mfma_f32_16x16x32_bf16(af, b0, acc[0], 0, 0, 0); \
            acc[1] = __builtin_amdgcn_mfma_f32_16x16x32_bf16(af, b1, acc[1], 0, 0, 0); \
            acc[2] = __builtin_amdgcn_mfma_f32_16x16x32_bf16(af, b2, acc[2], 0, 0, 0); \
            acc[3] = __builtin_amdgcn_mfma_f32_16x16x32_bf16(af, b3, acc[3], 0, 0, 0); \
        }                                                                       \
    } while (0)

    const int rsel = lane & 15;
    const int ksel = (lane >> 4) * 16;   // byte offset of lane's 8 bf16 in a B row

    // prologue: B(0) then A(0) (B first so WRITE_B's vmcnt wait leaves A in
    // flight); stage B(0) into buffer 0.
    ISSUE_B(0);
    ISSUE_A(0, avA);
    WRITE_B(0);

#pragma unroll 1
    for (int s = 0; s < 9; ++s) {
        // issue next step's loads; they stay in flight across the barrier.
        if (s < 8) {
            ISSUE_B(s + 1);
            if ((s & 1) == 0) ISSUE_A(s + 1, avB);
            else              ISSUE_A(s + 1, avA);
        }

        BARRIER_KEEP_VMEM();  // lds[s&1] B-writes (prev iter / prologue) visible

        const unsigned char* L = lds[s & 1];
        if ((s & 1) == 0) COMPUTE(L, avA);
        else              COMPUTE(L, avB);

        // write step s+1's B into the other buffer; its previous readers all
        // passed the barrier above. One barrier per step total.
        if (s < 8) WRITE_B((s + 1) & 1);
    }

    // epilogue: D layout col=lane&15, row=(lane>>4)*4+reg (m89-verified)
    const int col = lane & 15;
    const int rb  = (lane >> 4) * 4;
#pragma unroll
    for (int n = 0; n < 4; ++n)
#pragma unroll
        for (int i = 0; i < 4; ++i) {
            const int row = wave * 16 + rb + i;   // batch index
            const int f   = n * 16 + col;         // fout index
            Out[((size_t)row * 900 + l) * 64 + f] = acc[n][i];
        }
}

extern "C" void kernel_launch(void* const* d_in, const int* in_sizes, int n_in,
                              void* d_out, int out_size, void* d_ws, size_t ws_size,
                              hipStream_t stream) {
    const float* X  = (const float*)d_in[0];   // [128,32,32,64]
    const float* Fl = (const float*)d_in[1];   // [900,576,64]
    float* Out = (float*)d_out;                // [128,30,30,64]
    lc_mfma_kernel<<<dim3(900), dim3(512), 0, stream>>>(X, Fl, Out);
}